// Round 2
// baseline (855.293 us; speedup 1.0000x reference)
//
#include <hip/hip_runtime.h>
#include <hip/hip_bf16.h>
#include <cstdint>
#include <cstddef>

#define B_ 128
#define S_ 256
#define TOK (B_*S_)   // 32768

__device__ __forceinline__ float sigf(float x) {
    return __builtin_amdgcn_rcpf(1.0f + __expf(-x));
}
__device__ __forceinline__ float tanhfast(float x) {
    return 1.0f - 2.0f * __builtin_amdgcn_rcpf(1.0f + __expf(2.0f * x));
}

// ---- K1: char input-gate table: gin[dir][c][row] = b[row] + Wih[row,:]·emb[c,:]
__global__ void k_gin(const float* __restrict__ ce,
                      const float* __restrict__ wih_f, const float* __restrict__ b_f,
                      const float* __restrict__ wih_b, const float* __restrict__ b_b,
                      float* __restrict__ gin) {
    int tid = blockIdx.x * blockDim.x + threadIdx.x;
    if (tid >= 200) return;
    int dir = tid / 100, row = tid % 100;
    const float* wih = dir ? wih_b : wih_f;
    float bias = dir ? b_b[row] : b_f[row];
    for (int c = 0; c < 100; ++c) {
        float s = bias;
#pragma unroll
        for (int k = 0; k < 25; ++k) s += wih[row*25 + k] * ce[c*25 + k];
        gin[(dir*100 + c)*100 + row] = s;
    }
}

// ---- K1b: combined word-input weight [800][152] (k-padded) + bias [800]
__global__ void k_wcomb(const float* __restrict__ wih_f, const float* __restrict__ bf,
                        const float* __restrict__ wih_b, const float* __restrict__ bb,
                        float* __restrict__ Wc, float* __restrict__ bc) {
    int idx = blockIdx.x * blockDim.x + threadIdx.x;
    if (idx < 800*152) {
        int n = idx / 152, k = idx - n*152;
        int dir = n >= 400 ? 1 : 0, r = n - dir*400;
        const float* w = dir ? wih_b : wih_f;
        Wc[idx] = (k < 150) ? w[r*150 + k] : 0.0f;
    }
    if (idx < 800) {
        int dir = idx >= 400 ? 1 : 0, r = idx - dir*400;
        bc[idx] = dir ? bb[r] : bf[r];
    }
}

// ---- K2: char BiLSTM. 8 groups of 32 lanes per block; 25 active lanes per (word,dir).
__global__ __launch_bounds__(256, 1) void k_char(
        const float* __restrict__ gin,
        const float* __restrict__ whh_f, const float* __restrict__ whh_b,
        const int* __restrict__ char_ids, const int* __restrict__ word_num,
        float* __restrict__ wfbuf) {
    int tid  = threadIdx.x;
    int grp  = tid >> 5, lane = tid & 31;
    int g    = blockIdx.x * 8 + grp;        // (word,dir) id: 0..65535
    int word = g >> 1, dir = g & 1;
    int b    = word >> 8, s = word & 255;
    const float* whh = dir ? whh_b : whh_f;
    int k = (lane < 25) ? lane : 0;
    float wi[25], wf[25], wg[25], wo[25];
#pragma unroll
    for (int j = 0; j < 25; ++j) {
        wi[j] = whh[(k     )*25 + j];
        wf[j] = whh[(25 + k)*25 + j];
        wg[j] = whh[(50 + k)*25 + j];
        wo[j] = whh[(75 + k)*25 + j];
    }
    float h = 0.f, c = 0.f;
    const int* cid = char_ids + word*16;
    int base = tid & 32;   // wave-local 32-group base for shuffles
    for (int tt = 0; tt < 16; ++tt) {
        int t  = dir ? (15 - tt) : tt;
        int ch = cid[t];
        const float* gv = gin + (dir*100 + ch)*100;
        float ai = gv[k], af = gv[25 + k], ag = gv[50 + k], ao = gv[75 + k];
#pragma unroll
        for (int j = 0; j < 25; ++j) {
            float hj = __shfl(h, base + j, 64);
            ai += wi[j]*hj; af += wf[j]*hj; ag += wg[j]*hj; ao += wo[j]*hj;
        }
        c = sigf(af)*c + sigf(ai)*tanhfast(ag);
        h = sigf(ao)*tanhfast(c);
    }
    if (lane < 25) {
        float m = (s < word_num[b]) ? 1.f : 0.f;
        wfbuf[(size_t)word*152 + 100 + dir*25 + lane] = h * m;  // [hf | hb], masked
    }
}

// ---- K3a: gather word embeddings into wfbuf[:,0:100]; zero k-pad 150..151
__global__ void k_gather(const float* __restrict__ we, const int* __restrict__ wids,
                         float* __restrict__ wfbuf) {
    int idx = blockIdx.x * blockDim.x + threadIdx.x;
    if (idx >= TOK*152) return;
    int t = idx / 152, e = idx - t*152;
    if (e < 100)        wfbuf[idx] = we[(size_t)wids[t]*100 + e];
    else if (e >= 150)  wfbuf[idx] = 0.f;
}

// ---- K3b: word input gates GEMM  [32768,152] @ [152,800] -> bf16 gates
__global__ __launch_bounds__(256) void k_gemm_in(
        const float* __restrict__ A, const float* __restrict__ Wc,
        const float* __restrict__ bc, __hip_bfloat16* __restrict__ gates) {
    __shared__ float As[8][64];
    __shared__ float Bs[8][64];
    int tid = threadIdx.x;
    int tileM = blockIdx.x & 511;
    int tileN = blockIdx.x >> 9;        // 0..12
    int m0 = tileM*64, n0 = tileN*64;
    int ty = tid >> 4, tx = tid & 15;
    int a_m = tid >> 2, a_k = (tid & 3)*2;
    float acc[4][4] = {};
    for (int k0 = 0; k0 < 152; k0 += 8) {
        float2 av = *(const float2*)&A[(size_t)(m0 + a_m)*152 + k0 + a_k];
        float2 bv = make_float2(0.f, 0.f);
        if (n0 + a_m < 800)
            bv = *(const float2*)&Wc[(size_t)(n0 + a_m)*152 + k0 + a_k];
        __syncthreads();
        As[a_k][a_m] = av.x; As[a_k+1][a_m] = av.y;
        Bs[a_k][a_m] = bv.x; Bs[a_k+1][a_m] = bv.y;
        __syncthreads();
#pragma unroll
        for (int kk = 0; kk < 8; ++kk) {
            float4 a4 = *(const float4*)&As[kk][ty*4];
            float4 b4 = *(const float4*)&Bs[kk][tx*4];
            float am[4] = {a4.x, a4.y, a4.z, a4.w};
            float bn[4] = {b4.x, b4.y, b4.z, b4.w};
#pragma unroll
            for (int p = 0; p < 4; ++p)
#pragma unroll
                for (int q = 0; q < 4; ++q) acc[p][q] += am[p]*bn[q];
        }
    }
#pragma unroll
    for (int p = 0; p < 4; ++p) {
        int m = m0 + ty*4 + p;
#pragma unroll
        for (int q = 0; q < 4; ++q) {
            int n = n0 + tx*4 + q;
            if (n < 800) {
                int dir = n >= 400 ? 1 : 0, r = n - dir*400;
                gates[((size_t)dir*TOK + m)*400 + r] = __float2bfloat16(acc[p][q] + bc[n]);
            }
        }
    }
}

// ---- K4: word BiLSTM recurrence. 256 blocks = (b,dir); thread j<400 owns Whh row j.
__global__ __launch_bounds__(512, 1) void k_word(
        const __hip_bfloat16* __restrict__ gates,
        const float* __restrict__ whh_f, const float* __restrict__ whh_b,
        __hip_bfloat16* __restrict__ wh) {
    int b = blockIdx.x >> 1, dir = blockIdx.x & 1;
    int j = threadIdx.x;
    const float* whh = dir ? whh_b : whh_f;
    __shared__ __align__(16) float hs[100];
    __shared__ float gs[400];
    float4 w[25];
    if (j < 400) {
        const float4* wr = (const float4*)(whh + (size_t)j*100);
#pragma unroll
        for (int k = 0; k < 25; ++k) w[k] = wr[k];
    }
    float c = 0.f;
    if (j < 100) hs[j] = 0.f;
    __syncthreads();
    const __hip_bfloat16* gp = gates + ((size_t)dir*TOK + b*256)*400;
    for (int tt = 0; tt < 256; ++tt) {
        int t = dir ? (255 - tt) : tt;
        if (j < 400) {
            float acc = __bfloat162float(gp[(size_t)t*400 + j]);
            const float4* h4p = (const float4*)hs;
#pragma unroll
            for (int k = 0; k < 25; ++k) {
                float4 h4 = h4p[k];
                acc += w[k].x*h4.x + w[k].y*h4.y + w[k].z*h4.z + w[k].w*h4.w;
            }
            gs[j] = acc;
        }
        __syncthreads();
        if (j < 100) {
            float gi = gs[j], gf = gs[100+j], gg = gs[200+j], go = gs[300+j];
            c = sigf(gf)*c + sigf(gi)*tanhfast(gg);
            float h = sigf(go)*tanhfast(c);
            hs[j] = h;
            wh[(size_t)(b*256 + t)*200 + dir*100 + j] = __float2bfloat16(h);
        }
        __syncthreads();
    }
}

// ---- K5: feats = (tanh(wh@W1^T+b1)@W2^T+b2)*mask ; 32 tokens per block
__global__ __launch_bounds__(256) void k_feats(
        const __hip_bfloat16* __restrict__ wh,
        const float* __restrict__ W1, const float* __restrict__ b1,
        const float* __restrict__ W2, const float* __restrict__ b2,
        const int* __restrict__ word_num, float* __restrict__ feats) {
    __shared__ float As[8][32];
    __shared__ float Ws[8][100];
    __shared__ float mids[32][100];
    int tid = threadIdx.x;
    int m0  = blockIdx.x * 32;
    int a_m = tid >> 3, a_k = tid & 7;
    int tn  = tid % 25, tm = tid / 25;   // active: tid < 200
    float acc[4][4] = {};
    for (int k0 = 0; k0 < 200; k0 += 8) {
        float av = __bfloat162float(wh[(size_t)(m0 + a_m)*200 + k0 + a_k]);
        int i1 = tid + 256, i2 = tid + 512, i3 = tid + 768;
        float wv0 = W1[(tid>>3)*200 + k0 + (tid&7)];
        float wv1 = W1[(i1 >>3)*200 + k0 + (i1 &7)];
        float wv2 = W1[(i2 >>3)*200 + k0 + (i2 &7)];
        float wv3 = (i3 < 800) ? W1[(i3>>3)*200 + k0 + (i3&7)] : 0.f;
        __syncthreads();
        As[a_k][a_m] = av;
        Ws[tid&7][tid>>3] = wv0;
        Ws[i1 &7][i1 >>3] = wv1;
        Ws[i2 &7][i2 >>3] = wv2;
        if (i3 < 800) Ws[i3&7][i3>>3] = wv3;
        __syncthreads();
        if (tid < 200) {
#pragma unroll
            for (int kk = 0; kk < 8; ++kk) {
                float4 a4 = *(const float4*)&As[kk][tm*4];
                float4 w4 = *(const float4*)&Ws[kk][tn*4];
                float am[4] = {a4.x, a4.y, a4.z, a4.w};
                float wn[4] = {w4.x, w4.y, w4.z, w4.w};
#pragma unroll
                for (int p = 0; p < 4; ++p)
#pragma unroll
                    for (int q = 0; q < 4; ++q) acc[p][q] += am[p]*wn[q];
            }
        }
    }
    if (tid < 200) {
#pragma unroll
        for (int p = 0; p < 4; ++p)
#pragma unroll
            for (int q = 0; q < 4; ++q)
                mids[tm*4+p][tn*4+q] = tanhfast(acc[p][q] + b1[tn*4+q]);
    }
    __syncthreads();
    for (int idx = tid; idx < 288; idx += 256) {
        int tok = idx / 9, lab = idx - tok*9;
        int m = m0 + tok, bb = m >> 8, s = m & 255;
        float v = b2[lab];
        const float4* mp = (const float4*)mids[tok];
        const float4* wp = (const float4*)(W2 + lab*100);
#pragma unroll
        for (int k = 0; k < 25; ++k) {
            float4 mv = mp[k], wv = wp[k];
            v += mv.x*wv.x + mv.y*wv.y + mv.z*wv.z + mv.w*wv.w;
        }
        feats[(size_t)m*12 + lab] = (s < word_num[bb]) ? v : 0.f;
    }
}

// ---- K6: CRF numerator + log-forward recursion. One wave per batch row.
__global__ __launch_bounds__(64) void k_crf(
        const float* __restrict__ feats, const float* __restrict__ T,
        const int* __restrict__ word_num, const int* __restrict__ label_ids,
        float* __restrict__ perb) {
    int b = blockIdx.x, lane = threadIdx.x;
    int n = word_num[b];
    const int*   lab = label_ids + b*256;
    const float* fb  = feats + (size_t)b*256*12;
    // numerator (gold path score)
    float nm = 0.f;
    for (int t = lane; t < n; t += 64) {
        int lt = lab[t];
        int lp = (t == 0) ? 9 : lab[t-1];
        nm += fb[t*12 + lt] + T[lp*11 + lt];
    }
#pragma unroll
    for (int o = 32; o > 0; o >>= 1) nm += __shfl_down(nm, o, 64);
    nm = __shfl(nm, 0, 64);
    nm += T[lab[n-1]*11 + 10];
    // forward algorithm: lane j<11 owns target label j
    int j = lane;
    float Tc[11];
#pragma unroll
    for (int i = 0; i < 11; ++i) Tc[i] = T[i*11 + (j < 11 ? j : 0)];
    float alpha = (j == 9) ? 0.f : -1000.f;
    for (int t = 0; t < n; ++t) {
        float obs = (j < 9) ? fb[t*12 + j] : -1000.f;
        float v[11], mx = -1e30f;
#pragma unroll
        for (int i = 0; i < 11; ++i) { v[i] = __shfl(alpha, i, 64) + Tc[i]; mx = fmaxf(mx, v[i]); }
        float ssum = 0.f;
#pragma unroll
        for (int i = 0; i < 11; ++i) ssum += __expf(v[i] - mx);
        alpha = obs + mx + __logf(ssum);
    }
    float vv[11], mx = -1e30f, ssum = 0.f;
#pragma unroll
    for (int i = 0; i < 11; ++i) { vv[i] = __shfl(alpha, i, 64) + Tc[i]; mx = fmaxf(mx, vv[i]); }
#pragma unroll
    for (int i = 0; i < 11; ++i) ssum += __expf(vv[i] - mx);
    float denom = __shfl(mx + __logf(ssum), 10, 64);   // lane10's Tc = T[:,10]
    if (lane == 0) perb[b] = denom - nm;
}

// ---- K7: mean over batch
__global__ void k_reduce(const float* __restrict__ perb, float* __restrict__ out) {
    int t = threadIdx.x;
    float v = perb[t];
#pragma unroll
    for (int o = 32; o > 0; o >>= 1) v += __shfl_down(v, o, 64);
    __shared__ float sm[2];
    if ((t & 63) == 0) sm[t >> 6] = v;
    __syncthreads();
    if (t == 0) out[0] = (sm[0] + sm[1]) * (1.0f/128.0f);
}

extern "C" void kernel_launch(void* const* d_in, const int* in_sizes, int n_in,
                              void* d_out, int out_size, void* d_ws, size_t ws_size,
                              hipStream_t stream) {
    const float* word_emb = (const float*)d_in[0];
    const float* char_emb = (const float*)d_in[1];
    const float* cWih_f   = (const float*)d_in[2];
    const float* cWhh_f   = (const float*)d_in[3];
    const float* cb_f     = (const float*)d_in[4];
    const float* cWih_b   = (const float*)d_in[5];
    const float* cWhh_b   = (const float*)d_in[6];
    const float* cb_b     = (const float*)d_in[7];
    const float* wWih_f   = (const float*)d_in[8];
    const float* wWhh_f   = (const float*)d_in[9];
    const float* wb_f     = (const float*)d_in[10];
    const float* wWih_b   = (const float*)d_in[11];
    const float* wWhh_b   = (const float*)d_in[12];
    const float* wb_b     = (const float*)d_in[13];
    const float* W1       = (const float*)d_in[14];
    const float* b1       = (const float*)d_in[15];
    const float* W2       = (const float*)d_in[16];
    const float* b2       = (const float*)d_in[17];
    const float* T        = (const float*)d_in[18];
    const int* word_num   = (const int*)d_in[19];
    const int* word_ids   = (const int*)d_in[20];
    const int* char_ids   = (const int*)d_in[21];
    const int* label_ids  = (const int*)d_in[22];

    char* ws = (char*)d_ws;
    float* gin            = (float*)(ws);                       //    80,000 B
    float* Wc             = (float*)(ws + 80000);               //   486,400 B
    float* bc             = (float*)(ws + 566400);              //     3,200 B
    float* wfbuf          = (float*)(ws + 569600);              // 19,922,944 B [32768][152]
    __hip_bfloat16* gates = (__hip_bfloat16*)(ws + 20492544);   // 52,428,800 B [2][32768][400]
    __hip_bfloat16* wh    = (__hip_bfloat16*)(ws + 72921344);   // 13,107,200 B [32768][200]
    float* feats          = (float*)(ws + 86028544);            //  1,572,864 B [32768][12]
    float* perb           = (float*)(ws + 87601408);            //       512 B

    k_gin   <<<4, 64, 0, stream>>>(char_emb, cWih_f, cb_f, cWih_b, cb_b, gin);
    k_wcomb <<<(800*152 + 255)/256, 256, 0, stream>>>(wWih_f, wb_f, wWih_b, wb_b, Wc, bc);
    k_gather<<<(TOK*152)/256, 256, 0, stream>>>(word_emb, word_ids, wfbuf);
    k_char  <<<8192, 256, 0, stream>>>(gin, cWhh_f, cWhh_b, char_ids, word_num, wfbuf);
    k_gemm_in<<<512*13, 256, 0, stream>>>(wfbuf, Wc, bc, gates);
    k_word  <<<256, 512, 0, stream>>>(gates, wWhh_f, wWhh_b, wh);
    k_feats <<<1024, 256, 0, stream>>>(wh, W1, b1, W2, b2, word_num, feats);
    k_crf   <<<128, 64, 0, stream>>>(feats, T, word_num, label_ids, perb);
    k_reduce<<<1, 128, 0, stream>>>(perb, (float*)d_out);
}